// Round 2
// baseline (558.495 us; speedup 1.0000x reference)
//
#include <hip/hip_runtime.h>

// Divergence of a periodic 3-component field on a 256^3 grid, batch 2.
// out[b,z,y,x] = 0.5 * ( (u[z,y,x+1]-u[z,y,x-1])
//                      + (v[z,y+1,x]-v[z,y-1,x])
//                      + (w[z+1,y+1,x]-w[z-1,y-1,x]) ), all periodic.
//
// R3 == R2 resubmitted (R2 bench died with "container failed twice" — infra
// error, no kernel verdict). Theory being tested:
//  R1 (one tile per short-lived block, 5 loads in flight/wave) is
//  latency-bound, not BW-bound (547us vs ~85us roofline). Fix = MLP + persistence:
//  - 1024 persistent blocks (4/CU co-resident), each loops 16 iterations.
//  - 2 (z,yblk) tiles per iteration -> 10 independent f4 loads issued
//    back-to-back per wave before any use; unroll 2 lets the compiler overlap
//    next-iteration loads with current compute/stores (__restrict__).
//  - Keep R1's correct ideas: XCD z-chunking (cohort marches 4 z-planes/step,
//    w z+-1 halo reuse stays inside 4MB L2), shfl x-wrap, NT for read-once u
//    and write-once out, cached v/w (they carry all the reuse).
//  - All y-geometry hoisted out of the loop (y fixed per block); per-iteration
//    address math is wave-uniform -> SALU.

#define N     256
#define PLANE (N * N)
#define VOL   (N * N * N)

typedef float f4 __attribute__((ext_vector_type(4)));

__global__ __launch_bounds__(256, 4)
void calc_divergence_4406636445920_kernel(const float* __restrict__ x,
                                          float* __restrict__ out) {
    const int tx = threadIdx.x;            // lane in wave == x-position
    const int ty = threadIdx.y;
    const int x0 = tx << 2;
    const int lm = (tx + 63) & 63;         // lane for x0-1 (periodic)
    const int lp = (tx + 1) & 63;          // lane for x0+4 (periodic)

    const int chunk = blockIdx.x & 7;      // XCD (dispatch round-robin heuristic)
    const int cb    = blockIdx.x >> 3;     // 0..127 within chunk

    // Batch and z-range are constant per block: bz in [chunk*64, chunk*64+64)
    const int b     = chunk >> 2;          // 0..1
    const int zbase = (chunk & 3) << 6;    // z = zbase + zl, zl in [0,64)

    const float* __restrict__ u = x + (size_t)(b * 3 + 0) * VOL;
    const float* __restrict__ v = x + (size_t)(b * 3 + 1) * VOL;
    const float* __restrict__ w = x + (size_t)(b * 3 + 2) * VOL;
    float* __restrict__ ob      = out + (size_t)b * VOL;

    // y geometry fixed for the whole block lifetime (ypair == cb & 31)
    const int ypair = cb & 31;
    const int yA  = ((ypair)      << 2) + ty;   // 0..127
    const int yB  = ((ypair + 32) << 2) + ty;   // 128..255
    const int yAm = (yA == 0)     ? N - 1 : yA - 1;
    const int yAp = (yA == N - 1) ? 0     : yA + 1;
    const int yBm = (yB == 0)     ? N - 1 : yB - 1;
    const int yBp = (yB == N - 1) ? 0     : yB + 1;

    const int ryA  = yA  * N + x0;
    const int ryAp = yAp * N + x0;
    const int ryAm = yAm * N + x0;
    const int ryB  = yB  * N + x0;
    const int ryBp = yBp * N + x0;
    const int ryBm = yBm * N + x0;

    // Tile-pair index p = zl*32 + ypair; this block owns p = cb, cb+128, ...
    // Cohort of a chunk's 128 blocks covers 4 consecutive z-planes per step.
#pragma unroll 2
    for (int p = cb; p < 2048; p += 128) {
        const int zl = p >> 5;             // 0..63
        const int z  = zbase + zl;
        const int zm = (z == 0)     ? N - 1 : z - 1;
        const int zp = (z == N - 1) ? 0     : z + 1;

        const size_t rz  = (size_t)z  * PLANE;
        const size_t rzp = (size_t)zp * PLANE;
        const size_t rzm = (size_t)zm * PLANE;

        // 10 independent vector loads issued back-to-back (MLP)
        const f4 uA  = __builtin_nontemporal_load((const f4*)(u + rz + ryA));
        const f4 uB  = __builtin_nontemporal_load((const f4*)(u + rz + ryB));
        const f4 vpA = *(const f4*)(v + rz + ryAp);
        const f4 vmA = *(const f4*)(v + rz + ryAm);
        const f4 vpB = *(const f4*)(v + rz + ryBp);
        const f4 vmB = *(const f4*)(v + rz + ryBm);
        const f4 wpA = *(const f4*)(w + rzp + ryAp);
        const f4 wmA = *(const f4*)(w + rzm + ryAm);
        const f4 wpB = *(const f4*)(w + rzp + ryBp);
        const f4 wmB = *(const f4*)(w + rzm + ryBm);

        // periodic x neighbors via lane shuffle (wave wrap == periodic wrap)
        const float ulA = __shfl(uA.w, lm);   // u[x0-1]
        const float urA = __shfl(uA.x, lp);   // u[x0+4]
        const float ulB = __shfl(uB.w, lm);
        const float urB = __shfl(uB.x, lp);

        f4 oA, oB;
        oA.x = 0.5f * ((uA.y - ulA)  + (vpA.x - vmA.x) + (wpA.x - wmA.x));
        oA.y = 0.5f * ((uA.z - uA.x) + (vpA.y - vmA.y) + (wpA.y - wmA.y));
        oA.z = 0.5f * ((uA.w - uA.y) + (vpA.z - vmA.z) + (wpA.z - wmA.z));
        oA.w = 0.5f * ((urA  - uA.z) + (vpA.w - vmA.w) + (wpA.w - wmA.w));

        oB.x = 0.5f * ((uB.y - ulB)  + (vpB.x - vmB.x) + (wpB.x - wmB.x));
        oB.y = 0.5f * ((uB.z - uB.x) + (vpB.y - vmB.y) + (wpB.y - wmB.y));
        oB.z = 0.5f * ((uB.w - uB.y) + (vpB.z - vmB.z) + (wpB.z - wmB.z));
        oB.w = 0.5f * ((urB  - uB.z) + (vpB.w - vmB.w) + (wpB.w - wmB.w));

        __builtin_nontemporal_store(oA, (f4*)(ob + rz + ryA));
        __builtin_nontemporal_store(oB, (f4*)(ob + rz + ryB));
    }
}

extern "C" void kernel_launch(void* const* d_in, const int* in_sizes, int n_in,
                              void* d_out, int out_size, void* d_ws, size_t ws_size,
                              hipStream_t stream) {
    const float* xin = (const float*)d_in[0];
    float* o = (float*)d_out;

    dim3 block(64, 4, 1);
    dim3 grid(1024, 1, 1);   // persistent: 4 blocks/CU co-resident, 16 iters each

    calc_divergence_4406636445920_kernel<<<grid, block, 0, stream>>>(xin, o);
}

// Round 3
// 550.487 us; speedup vs baseline: 1.0145x; 1.0145x over previous
//
#include <hip/hip_runtime.h>

// Divergence of a periodic 3-component field on a 256^3 grid, batch 2.
// out[b,z,y,x] = 0.5 * ( (u[z,y,x+1]-u[z,y,x-1])
//                      + (v[z,y+1,x]-v[z,y-1,x])
//                      + (w[z+1,y+1,x]-w[z-1,y-1,x]) ), all periodic.
//
// R4 = exact revert to the R1 structure (best measured: 547.2 us).
// R2/R3 post-mortem: dur_us times the whole graph — two ~247us harness
// re-poison fills (~494us, fixed) + the kernel itself (~53-64us; it never
// appears in the top-5 dispatch table, so its device time is < 246us).
// The persistent/deep-MLP R3 variant made the KERNEL ~20% slower (loop-carried
// scheduling, 32x fewer waves); R1's 32768 short blocks already provide ample
// memory-level parallelism and run below the cold-cache HBM roofline thanks to
// L2/L3 serving the v/w halo re-reads.
//
// Layout (R1, confirmed good):
//  - 1D grid with XCD swizzle: lin%8 picks a 64-plane z-chunk so each XCD's
//    L2 streams contiguous z; the w z+1 halo plane is re-read 2 z-steps
//    later from the same L2/L3 (~small reuse distance).
//  - One wave == one periodic x-row (64 lanes x float4) -> x-wrap neighbors
//    come from __shfl with mod-64 lane wrap, no edge loads.
//  - u is read exactly once, out written once -> non-temporal, keep L2/L3
//    capacity for the reused v/w halo rows/planes.

#define N     256
#define PLANE (N * N)
#define VOL   (N * N * N)

typedef float f4 __attribute__((ext_vector_type(4)));

__global__ __launch_bounds__(256)
void calc_divergence_4406636445920_kernel(const float* __restrict__ x,
                                          float* __restrict__ out) {
    const int tx = threadIdx.x;            // lane in wave == x-position
    const int x0 = tx << 2;

    // XCD-aware swizzle: lin%8 -> z-chunk, then y-blocks fastest within a z.
    const int lin   = blockIdx.x;          // 0..32767
    const int chunk = lin & 7;             // -> XCD (heuristic)
    const int s     = lin >> 3;            // 0..4095 within chunk
    const int yblk  = s & 63;              // 64 y-blocks of 4 rows
    const int bz    = chunk * 64 + (s >> 6);   // 0..511
    const int z     = bz & (N - 1);
    const int b     = bz >> 8;
    const int y     = (yblk << 2) + threadIdx.y;

    const float* __restrict__ u = x + (size_t)(b * 3 + 0) * VOL;
    const float* __restrict__ v = x + (size_t)(b * 3 + 1) * VOL;
    const float* __restrict__ w = x + (size_t)(b * 3 + 2) * VOL;

    const int ym = (y == 0)     ? N - 1 : y - 1;
    const int yp = (y == N - 1) ? 0     : y + 1;
    const int zm = (z == 0)     ? N - 1 : z - 1;
    const int zp = (z == N - 1) ? 0     : z + 1;

    const int rowz = z * PLANE;
    const int rowc = rowz + y * N;

    // u: one NT vector load; x+-1 via lane shuffle (wave wrap == periodic wrap)
    const f4 uc = __builtin_nontemporal_load((const f4*)(u + rowc + x0));
    const float ul = __shfl(uc.w, (tx + 63) & 63);   // u[x0-1] (periodic)
    const float ur = __shfl(uc.x, (tx + 1)  & 63);   // u[x0+4] (periodic)

    const f4 vp = *(const f4*)(v + rowz + yp * N + x0);
    const f4 vm = *(const f4*)(v + rowz + ym * N + x0);
    const f4 wp = *(const f4*)(w + zp * PLANE + yp * N + x0);
    const f4 wm = *(const f4*)(w + zm * PLANE + ym * N + x0);

    f4 o;
    o.x = 0.5f * ((uc.y - ul)   + (vp.x - vm.x) + (wp.x - wm.x));
    o.y = 0.5f * ((uc.z - uc.x) + (vp.y - vm.y) + (wp.y - wm.y));
    o.z = 0.5f * ((uc.w - uc.y) + (vp.z - vm.z) + (wp.z - wm.z));
    o.w = 0.5f * ((ur   - uc.z) + (vp.w - vm.w) + (wp.w - wm.w));

    __builtin_nontemporal_store(o, (f4*)(out + (size_t)b * VOL + rowc + x0));
}

extern "C" void kernel_launch(void* const* d_in, const int* in_sizes, int n_in,
                              void* d_out, int out_size, void* d_ws, size_t ws_size,
                              hipStream_t stream) {
    const float* xin = (const float*)d_in[0];
    float* out = (float*)d_out;

    dim3 block(64, 4, 1);
    dim3 grid(2 * N * (N / 4), 1, 1);   // 32768 blocks, swizzled in-kernel

    calc_divergence_4406636445920_kernel<<<grid, block, 0, stream>>>(xin, out);
}